// Round 4
// baseline (401.158 us; speedup 1.0000x reference)
//
#include <hip/hip_runtime.h>
#include <math.h>

// Problem constants (fixed by the reference: [16,3,1024,1024] fp32 inputs)
#define NP      8
#define NBINS   256
#define BC      48
#define HH      1024
#define WW      1024
#define RPB     32                  // rows per block (32 | 128 -> one h-patch per block)
#define THREADS 256
#define NBLK1   1536                // BC*HH / RPB
#define BLK_PER_I 192               // NBLK1 / NP  (blocks sharing one h-patch index)
#define U       4                   // rows per DMA stage group
#define NG      (RPB / U)           // 8 groups per block
#define ROWB    4096                // bytes per image row (1024 fp32)
#define PATCH_ELEMS (BC * 128 * 128)
#define N_TOTAL ((long long)BC * HH * WW)

// ---- workspace layout (Path A: per-block hist dump, no global atomics) ----
#define GH_BYTES   ((size_t)NBLK1 * 2048 * 2)          // u16 hist per block: 6.29 MB
#define GS_OFF     GH_BYTES
#define GS_BYTES   ((size_t)NBLK1 * NP * 4)            // per-block 8 j-sums
#define ENT_OFF    (GS_OFF + GS_BYTES)                 // 8-byte aligned
#define ENT_BYTES  (64 * 8)
#define GT_OFF     (ENT_OFF + ENT_BYTES)
#define PATHA_BYTES (GT_OFF + 64 * 4)
// ---- Path B (fallback, tiny ws): atomic flush ----
#define B_GHIST_BYTES (64 * NBINS * 4)                 // 64 KB
#define B_GSUM_OFF    B_GHIST_BYTES
#define B_ENT_OFF     (B_GSUM_OFF + 256)               // 8-aligned

typedef float f4 __attribute__((ext_vector_type(4)));

// DMA one stage group: U=4 rows of both streams -> LDS, fire-and-forget.
// Wave w: stream = w>>1, rows u0..u0+1 (u0 = (w&1)*2), 4 chunks of 1 KB per row.
// LDS dest is wave-uniform base + lane*16 (HW adds the lane offset, m104/m108);
// global src is per-lane (base + lane*16). Linear LDS layout, no padding.
__device__ __forceinline__ void stage_group(const char* sr, const char* hr,
                                            int grow, char* lds_buf,
                                            int w, int lane)
{
    const char* gb = (w >> 1) ? hr : sr;
    const int   ss = (w >> 1);
    const int   u0 = (w & 1) * 2;
#pragma unroll
    for (int du = 0; du < 2; ++du) {
        const int u = u0 + du;
        const char* gp = gb + (size_t)(grow + u) * ROWB + (size_t)lane * 16;
        char* lp = lds_buf + (ss * U + u) * ROWB;
#pragma unroll
        for (int c = 0; c < 4; ++c) {
            __builtin_amdgcn_global_load_lds(
                (const __attribute__((address_space(1))) void*)(gp + c * 1024),
                (__attribute__((address_space(3))) void*)(lp + c * 1024),
                16, 0, 0);
        }
    }
}

// Pass 1: per-patch histogram + per-patch sum |sr-hr|, streamed via the
// global_load_lds DMA path (no VGPR return -> bypasses the per-CU load
// writeback service cap measured at ~5-6 B/cy across R0-R3 configs).
// Double-buffered 32 KB groups, counted vmcnt(8), raw s_barrier (no drain).
template <bool ATOMIC>
__global__ __launch_bounds__(THREADS)
void entrop_pass1(const float* __restrict__ sr, const float* __restrict__ hr,
                  unsigned int* __restrict__ gh32, float* __restrict__ gs)
{
    __shared__ __align__(16) char ldsbuf[2][2 * U * ROWB];   // 64 KB, [buf][stream|row]
    __shared__ unsigned int hist[NP * NBINS];                 // 8 KB

    const int t    = threadIdx.x;
    const int w    = t >> 6;
    const int lane = t & 63;
    const int r0   = blockIdx.x * RPB;
    const int i    = (r0 & (HH - 1)) >> 7;   // h-patch (block-uniform; 32 | 128)
    const int j    = t >> 5;                 // w-patch for this thread
    unsigned int* histj = &hist[j << 8];

    const char* sc = (const char*)sr;
    const char* hc = (const char*)hr;

    // Prologue: issue group 0 DMA first (latency hides under hist init),
    // then full-drain __syncthreads (also orders hist init vs atomics).
    stage_group(sc, hc, r0, ldsbuf[0], w, lane);
#pragma unroll
    for (int m = t; m < NP * NBINS; m += THREADS) hist[m] = 0;
    __syncthreads();

    float acc = 0.0f;
#pragma unroll 1
    for (int g = 0; g < NG; ++g) {
        if (g + 1 < NG) {
            stage_group(sc, hc, r0 + (g + 1) * U, ldsbuf[(g + 1) & 1], w, lane);
            asm volatile("s_waitcnt vmcnt(8)" ::: "memory");   // oldest 8 = group g
        } else {
            asm volatile("s_waitcnt vmcnt(0)" ::: "memory");   // final group
        }
        __builtin_amdgcn_s_barrier();                          // group g visible to all

        const char* bs = ldsbuf[g & 1];
#pragma unroll
        for (int u = 0; u < U; ++u) {
            f4 s = *(const f4*)(bs + u * ROWB + t * 16);
            f4 h = *(const f4*)(bs + (U + u) * ROWB + t * 16);
#pragma unroll
            for (int e = 0; e < 4; ++e) {
                acc += fabsf(s[e] - h[e]);
                int b = min(max((int)(h[e] * 255.0f), 0), 255);
                atomicAdd(&histj[b], 1u);
            }
        }
        __builtin_amdgcn_s_barrier();      // all done with buf before next overwrite
    }

    // reduce |d| within each 32-lane group (all lanes share j)
    for (int off = 16; off; off >>= 1) acc += __shfl_down(acc, off, 32);
    if ((t & 31) == 0) {
        if (ATOMIC) atomicAdd(&gs[i * NP + j], acc);
        else        gs[blockIdx.x * NP + j] = acc;
    }

    __syncthreads();
    if (ATOMIC) {
        for (int m = t; m < NP * NBINS; m += THREADS) {
            unsigned int c = hist[m];
            if (c) atomicAdd(&gh32[i * NP * NBINS + m], c);
        }
    } else {
        // pack 2 bins per u32 (counts <= RPB*128 = 4096 per block-bin), coalesced
#pragma unroll
        for (int m = t; m < NP * NBINS / 2; m += THREADS)
            gh32[(size_t)blockIdx.x * (NP * NBINS / 2) + m] =
                hist[2 * m] | (hist[2 * m + 1] << 16);
    }
}

// Path A reduce: 64 blocks, one per patch p=(i,jj). Sums 192 per-block u16
// hists -> counts -> fp64 entropy; sums 192 per-block j-sums -> gsumT.
// Blocks sharing h-patch i (RPB=32): b = 32u + 4i + e, u in [0,48), e in [0,4).
__global__ __launch_bounds__(THREADS)
void entrop_reduceA(const unsigned short* __restrict__ gh,
                    const float* __restrict__ gs,
                    double* __restrict__ ent, float* __restrict__ gsumT)
{
    const int p = blockIdx.x, i = p >> 3, jj = p & 7;
    const int t = threadIdx.x;

    unsigned int cnt = 0;
    const unsigned short* col = gh + jj * NBINS + t;
#pragma unroll 1
    for (int u = 0; u < 48; u += 4) {            // 16 independent loads per iter
#pragma unroll
        for (int v = 0; v < 4; ++v)
#pragma unroll
            for (int e = 0; e < 4; ++e)
                cnt += col[(size_t)(32 * (u + v) + 4 * i + e) * 2048];
    }
    double term = 0.0;
    if (cnt) {
        double pd = (double)cnt * (1.0 / (double)PATCH_ELEMS);
        term = pd * log2(pd);
    }

    float sg = 0.0f;
    if (t < BLK_PER_I) {                         // 192 < 256: one load per thread
        int u = t >> 2, e = t & 3;
        sg = gs[(size_t)(32 * u + 4 * i + e) * NP + jj];
    }

    for (int off = 32; off; off >>= 1) {
        term += __shfl_down(term, off, 64);
        sg   += __shfl_down(sg, off, 64);
    }
    __shared__ double rd[4];
    __shared__ float  rf[4];
    if ((t & 63) == 0) { rd[t >> 6] = term; rf[t >> 6] = sg; }
    __syncthreads();
    if (t == 0) {
        ent[p]   = -(rd[0] + rd[1] + rd[2] + rd[3]);
        gsumT[p] = rf[0] + rf[1] + rf[2] + rf[3];
    }
}

// Path B reduce: entropy from the atomically-accumulated u32 hist.
__global__ __launch_bounds__(THREADS)
void entrop_reduceB(const unsigned int* __restrict__ ghist, double* __restrict__ ent)
{
    const int p = blockIdx.x, t = threadIdx.x;
    unsigned int c = ghist[p * NBINS + t];
    double term = 0.0;
    if (c) {
        double pd = (double)c * (1.0 / (double)PATCH_ELEMS);
        term = pd * log2(pd);
    }
    for (int off = 32; off; off >>= 1) term += __shfl_down(term, off, 64);
    __shared__ double rd[4];
    if ((t & 63) == 0) rd[t >> 6] = term;
    __syncthreads();
    if (t == 0) ent[p] = -(rd[0] + rd[1] + rd[2] + rd[3]);
}

// Final: 1 wave. min/max over 64 entropies, weighted sum, scalar out.
__global__ void entrop_final(const double* __restrict__ ent,
                             const float* __restrict__ gsumT,
                             float* __restrict__ out)
{
    const int t = threadIdx.x;   // 64 threads
    double e = ent[t];
    double mn = e, mx = e;
#pragma unroll
    for (int off = 32; off; off >>= 1) {
        mn = fmin(mn, __shfl_xor(mn, off, 64));
        mx = fmax(mx, __shfl_xor(mx, off, 64));
    }
    double contrib = (e - mn) / mx * (double)gsumT[t];
#pragma unroll
    for (int off = 32; off; off >>= 1) contrib += __shfl_xor(contrib, off, 64);
    if (t == 0) out[0] = (float)(contrib / (double)N_TOTAL);
}

extern "C" void kernel_launch(void* const* d_in, const int* in_sizes, int n_in,
                              void* d_out, int out_size, void* d_ws, size_t ws_size,
                              hipStream_t stream)
{
    const float* sr = (const float*)d_in[0];
    const float* hr = (const float*)d_in[1];
    float* out = (float*)d_out;
    char* ws = (char*)d_ws;

    if (ws_size >= PATHA_BYTES) {
        unsigned int*   gh32  = (unsigned int*)ws;                 // u16 hists, u32-packed
        float*          gs    = (float*)(ws + GS_OFF);
        double*         ent   = (double*)(ws + ENT_OFF);
        float*          gsumT = (float*)(ws + GT_OFF);
        // everything fully overwritten before read -> no memset needed
        entrop_pass1<false><<<NBLK1, THREADS, 0, stream>>>(sr, hr, gh32, gs);
        entrop_reduceA<<<64, THREADS, 0, stream>>>((const unsigned short*)gh32, gs, ent, gsumT);
        entrop_final<<<1, 64, 0, stream>>>(ent, gsumT, out);
    } else {
        unsigned int* ghist = (unsigned int*)ws;
        float*        gsum  = (float*)(ws + B_GSUM_OFF);
        double*       ent   = (double*)(ws + B_ENT_OFF);
        hipMemsetAsync(ws, 0, B_GSUM_OFF + 256, stream);
        entrop_pass1<true><<<NBLK1, THREADS, 0, stream>>>(sr, hr, ghist, gsum);
        entrop_reduceB<<<64, THREADS, 0, stream>>>(ghist, ent);
        entrop_final<<<1, 64, 0, stream>>>(ent, gsum, out);
    }
}